// Round 2
// baseline (594.669 us; speedup 1.0000x reference)
//
#include <hip/hip_runtime.h>
#include <stdint.h>

#define DIM 128
#define LPAD 136   // padded LDS row stride for the fused small-level kernels (round-0 proven)

static constexpr long long NTOT = 299593LL;

using bf16x8 = __attribute__((ext_vector_type(8))) __bf16;
using f32x4  = __attribute__((ext_vector_type(4))) float;

__device__ __forceinline__ float relu(float x){ return x > 0.f ? x : 0.f; }
__device__ __forceinline__ __bf16 tobf(float x){ return (__bf16)x; }

__device__ __forceinline__ void mfma_acc(f32x4& acc, bf16x8 a, bf16x8 b){
    acc = __builtin_amdgcn_mfma_f32_16x16x32_bf16(a, b, acc, 0, 0, 0);
}

// copy 128x128 bf16 weight (row stride src_stride) into padded LDS (stride LPAD)
// -- used only by the fused small-level kernels (round-0 layout)
__device__ __forceinline__ void load_w_lds(const __bf16* __restrict__ wsrc,
                                           __bf16* lds, int src_stride){
    int t = threadIdx.x;
    #pragma unroll
    for (int i = 0; i < 8; ++i){
        int idx = t + i*256;                 // 2048 chunks of 8 bf16
        int row = idx >> 4, col8 = (idx & 15) << 3;
        *(uint4*)(&lds[row*LPAD + col8]) = *(const uint4*)(wsrc + row*src_stride + col8);
    }
}

// stage a 32KB frag-major weight into LDS: straight contiguous copy, conflict-free
template<int NTHR>
__device__ __forceinline__ void stage_fm(const __bf16* __restrict__ src, __bf16* lds){
    const int t = threadIdx.x;
    #pragma unroll
    for (int i = 0; i < 2048/NTHR; ++i){
        int c = i*NTHR + t;
        *((uint4*)lds + c) = *((const uint4*)src + c);
    }
}

// ---- prep: weights fp32->bf16 in BOTH row-major (fused kernels) and frag-major
// (streaming kernels) layouts; root ctx = ones.
// Frag-major: element (r,c) of a 128x128 weight -> ((nt*4+ks)*512 + lane*8 + j)
// with nt=r>>4, l15=r&15, ks=c>>5, quad=(c>>3)&3, j=c&7, lane=quad*16+l15.
__global__ __launch_bounds__(256) void prep_kernel(
    const float* __restrict__ Ws, const float* __restrict__ Wc,
    const float* __restrict__ Wx, const float* __restrict__ Wf,
    __bf16* __restrict__ wts, __bf16* __restrict__ ctx)
{
    int idx = blockIdx.x*256 + threadIdx.x;
    if (idx < 81920){
        float v;
        if      (idx < 16384) v = Ws[idx];
        else if (idx < 32768) v = Wc[idx - 16384];
        else if (idx < 49152) v = Wx[idx - 32768];
        else                  v = Wf[idx - 49152];
        wts[idx] = tobf(v);
    } else if (idx < 163840){
        int d2 = idx - 81920;
        int sel = d2 >> 14;                 // 0:Ws 1:Wc 2:Wx 3:Wf-h0 4:Wf-h1
        int d   = d2 & 16383;
        int j = d & 7, ln = (d >> 3) & 63, f = d >> 9;
        int r = (f >> 2)*16 + (ln & 15);
        int c = (f & 3)*32 + (ln >> 4)*8 + j;
        float v;
        if      (sel == 0) v = Ws[r*128 + c];
        else if (sel == 1) v = Wc[r*128 + c];
        else if (sel == 2) v = Wx[r*128 + c];
        else if (sel == 3) v = Wf[r*256 + c];
        else               v = Wf[r*256 + 128 + c];
        wts[idx] = tobf(v);
    } else if (idx < 163968){
        ctx[idx - 163840] = tobf(1.0f);     // root context row
    }
}

// ================== streaming kernels (leaf level + final) ==================
// Structure: stage weight (32KB frag-major) -> ONE barrier -> each wave
// independently grid-strides over 32-row tiles, batch-issuing all loads.

// up1: sib[g] = mean_s relu(Ws.child + bs); also materialize leaf agg = bf16(init)
__global__ __launch_bounds__(256, 4) void up1_kernel(
    const __bf16* __restrict__ wfm, const float* __restrict__ init,
    const float* __restrict__ bs, __bf16* __restrict__ agg,
    __bf16* __restrict__ sib, long long child_base)
{
    __shared__ __attribute__((aligned(16))) __bf16 lds_w[16384];
    stage_fm<256>(wfm, lds_w);
    __syncthreads();
    const int t = threadIdx.x, w = t>>6, lane = t&63, quad = lane>>4, l15 = lane&15;
    float bsr[8];
    #pragma unroll
    for (int nt = 0; nt < 8; ++nt) bsr[nt] = bs[nt*16 + l15];
    const int gw = blockIdx.x*4 + w;        // 4096 waves, 8192 tiles
    #pragma unroll 1
    for (int k = 0; k < 2; ++k){
        const long long tile = gw + k*4096;
        const long long r0 = tile*32;
        // batch-issue all 32 fp32 loads
        float4 v[2][4][2];
        #pragma unroll
        for (int tt = 0; tt < 2; ++tt){
            const float* p = init + (child_base + r0 + tt*16 + l15)*DIM + quad*8;
            #pragma unroll
            for (int ks = 0; ks < 4; ++ks){
                v[tt][ks][0] = *(const float4*)(p + ks*32);
                v[tt][ks][1] = *(const float4*)(p + ks*32 + 4);
            }
        }
        bf16x8 af[2][4];
        #pragma unroll
        for (int tt = 0; tt < 2; ++tt){
            const long long ob = (child_base + r0 + tt*16 + l15)*DIM + quad*8;
            #pragma unroll
            for (int ks = 0; ks < 4; ++ks){
                bf16x8 a;
                a[0]=tobf(v[tt][ks][0].x); a[1]=tobf(v[tt][ks][0].y);
                a[2]=tobf(v[tt][ks][0].z); a[3]=tobf(v[tt][ks][0].w);
                a[4]=tobf(v[tt][ks][1].x); a[5]=tobf(v[tt][ks][1].y);
                a[6]=tobf(v[tt][ks][1].z); a[7]=tobf(v[tt][ks][1].w);
                af[tt][ks] = a;
                *(uint4*)(agg + ob + ks*32) = *(uint4*)&a;   // leaf agg = bf16(init)
            }
        }
        f32x4 acc[2][8];
        #pragma unroll
        for (int tt = 0; tt < 2; ++tt)
            #pragma unroll
            for (int i = 0; i < 8; ++i) acc[tt][i] = f32x4{0.f,0.f,0.f,0.f};
        #pragma unroll
        for (int ks = 0; ks < 4; ++ks){
            #pragma unroll
            for (int nt = 0; nt < 8; ++nt){
                bf16x8 b = *(const bf16x8*)&lds_w[((nt*4+ks)<<9) + lane*8];
                mfma_acc(acc[0][nt], af[0][ks], b);
                mfma_acc(acc[1][nt], af[1][ks], b);
            }
        }
        // sibling mean: lane's 4 acc rows = one sibling group
        #pragma unroll
        for (int tt = 0; tt < 2; ++tt){
            const long long g = tile*8 + tt*4 + quad;
            #pragma unroll
            for (int nt = 0; nt < 8; ++nt){
                float b = bsr[nt];
                float s = relu(acc[tt][nt][0]+b) + relu(acc[tt][nt][1]+b)
                        + relu(acc[tt][nt][2]+b) + relu(acc[tt][nt][3]+b);
                sib[g*DIM + nt*16 + l15] = tobf(s*0.25f);
            }
        }
    }
}

// up2: agg[parent] = init[parent] + 0.5*(relu(Wc.sib_t0+bc) + relu(Wc.sib_t1+bc))
__global__ __launch_bounds__(256, 4) void up2_kernel(
    const __bf16* __restrict__ wfm, const float* __restrict__ init,
    const float* __restrict__ bc, const __bf16* __restrict__ sib,
    __bf16* __restrict__ agg, long long parent_base)
{
    __shared__ __attribute__((aligned(16))) __bf16 lds_w[16384];
    stage_fm<256>(wfm, lds_w);
    __syncthreads();
    const int t = threadIdx.x, w = t>>6, lane = t&63, quad = lane>>4, l15 = lane&15;
    float bcr[8];
    #pragma unroll
    for (int nt = 0; nt < 8; ++nt) bcr[nt] = bc[nt*16 + l15];
    const int gw = blockIdx.x*4 + w;        // 2048 waves = 2048 tiles exactly
    const long long r0 = (long long)gw*32;  // sib row base
    bf16x8 a[2][4];
    #pragma unroll
    for (int tt = 0; tt < 2; ++tt)
        #pragma unroll
        for (int ks = 0; ks < 4; ++ks)
            a[tt][ks] = *(const bf16x8*)(sib + (r0 + tt*16 + l15)*DIM + ks*32 + quad*8);
    f32x4 acc[2][8];
    #pragma unroll
    for (int tt = 0; tt < 2; ++tt)
        #pragma unroll
        for (int i = 0; i < 8; ++i) acc[tt][i] = f32x4{0.f,0.f,0.f,0.f};
    #pragma unroll
    for (int ks = 0; ks < 4; ++ks){
        #pragma unroll
        for (int nt = 0; nt < 8; ++nt){
            bf16x8 b = *(const bf16x8*)&lds_w[((nt*4+ks)<<9) + lane*8];
            mfma_acc(acc[0][nt], a[0][ks], b);
            mfma_acc(acc[1][nt], a[1][ks], b);
        }
    }
    #pragma unroll
    for (int tt = 0; tt < 2; ++tt){
        const long long p0 = r0/2 + tt*8 + quad*2;
        const long long p1 = p0 + 1;
        #pragma unroll
        for (int nt = 0; nt < 8; ++nt){
            int col = nt*16 + l15;
            float b = bcr[nt];
            float r0_ = relu(acc[tt][nt][0]+b), r1_ = relu(acc[tt][nt][1]+b);
            float r2_ = relu(acc[tt][nt][2]+b), r3_ = relu(acc[tt][nt][3]+b);
            long long gr0 = parent_base + p0, gr1 = parent_base + p1;
            agg[gr0*DIM + col] = tobf(init[gr0*DIM + col] + 0.5f*(r0_+r1_));
            agg[gr1*DIM + col] = tobf(init[gr1*DIM + col] + 0.5f*(r2_+r3_));
        }
    }
}

// down_h: ctxh[p] = relu(Wx.ctx[parent_base+p] + bx)  (bf16 tmp, local index)
__global__ __launch_bounds__(256, 4) void downh_kernel(
    const __bf16* __restrict__ wfm, const float* __restrict__ bx,
    const __bf16* __restrict__ ctx, __bf16* __restrict__ ctxh,
    long long parent_base)
{
    __shared__ __attribute__((aligned(16))) __bf16 lds_w[16384];
    stage_fm<256>(wfm, lds_w);
    __syncthreads();
    const int t = threadIdx.x, w = t>>6, lane = t&63, quad = lane>>4, l15 = lane&15;
    float bxr[8];
    #pragma unroll
    for (int nt = 0; nt < 8; ++nt) bxr[nt] = bx[nt*16 + l15];
    const int gw = blockIdx.x*4 + w;        // 1024 waves = 1024 tiles exactly
    const long long r0 = (long long)gw*32;
    bf16x8 a[2][4];
    #pragma unroll
    for (int tt = 0; tt < 2; ++tt)
        #pragma unroll
        for (int ks = 0; ks < 4; ++ks)
            a[tt][ks] = *(const bf16x8*)(ctx + (parent_base + r0 + tt*16 + l15)*DIM + ks*32 + quad*8);
    f32x4 acc[2][8];
    #pragma unroll
    for (int tt = 0; tt < 2; ++tt)
        #pragma unroll
        for (int i = 0; i < 8; ++i) acc[tt][i] = f32x4{0.f,0.f,0.f,0.f};
    #pragma unroll
    for (int ks = 0; ks < 4; ++ks){
        #pragma unroll
        for (int nt = 0; nt < 8; ++nt){
            bf16x8 b = *(const bf16x8*)&lds_w[((nt*4+ks)<<9) + lane*8];
            mfma_acc(acc[0][nt], a[0][ks], b);
            mfma_acc(acc[1][nt], a[1][ks], b);
        }
    }
    #pragma unroll
    for (int tt = 0; tt < 2; ++tt){
        #pragma unroll
        for (int nt = 0; nt < 8; ++nt){
            int col = nt*16 + l15;
            float b = bxr[nt];
            #pragma unroll
            for (int rg = 0; rg < 4; ++rg){
                long long row = r0 + tt*16 + quad*4 + rg;
                ctxh[row*DIM + col] = tobf(relu(acc[tt][nt][rg] + b));
            }
        }
    }
}

// down_c: ctx[child] = (ctxh[parent] + sum_sibs h - h_self)/4, h = relu(Wx.agg+bx)
__global__ __launch_bounds__(256, 4) void downc_kernel(
    const __bf16* __restrict__ wfm, const float* __restrict__ bx,
    const __bf16* __restrict__ agg, const __bf16* __restrict__ ctxh,
    __bf16* __restrict__ ctx, long long child_base)
{
    __shared__ __attribute__((aligned(16))) __bf16 lds_w[16384];
    stage_fm<256>(wfm, lds_w);
    __syncthreads();
    const int t = threadIdx.x, w = t>>6, lane = t&63, quad = lane>>4, l15 = lane&15;
    float bxr[8];
    #pragma unroll
    for (int nt = 0; nt < 8; ++nt) bxr[nt] = bx[nt*16 + l15];
    const int gw = blockIdx.x*4 + w;        // 4096 waves, 8192 tiles
    #pragma unroll 1
    for (int k = 0; k < 2; ++k){
        const long long tile = gw + k*4096;
        const long long r0 = tile*32;
        bf16x8 a[2][4];
        #pragma unroll
        for (int tt = 0; tt < 2; ++tt)
            #pragma unroll
            for (int ks = 0; ks < 4; ++ks)
                a[tt][ks] = *(const bf16x8*)(agg + (child_base + r0 + tt*16 + l15)*DIM + ks*32 + quad*8);
        f32x4 acc[2][8];
        #pragma unroll
        for (int tt = 0; tt < 2; ++tt)
            #pragma unroll
            for (int i = 0; i < 8; ++i) acc[tt][i] = f32x4{0.f,0.f,0.f,0.f};
        #pragma unroll
        for (int ks = 0; ks < 4; ++ks){
            #pragma unroll
            for (int nt = 0; nt < 8; ++nt){
                bf16x8 b = *(const bf16x8*)&lds_w[((nt*4+ks)<<9) + lane*8];
                mfma_acc(acc[0][nt], a[0][ks], b);
                mfma_acc(acc[1][nt], a[1][ks], b);
            }
        }
        #pragma unroll
        for (int tt = 0; tt < 2; ++tt){
            const long long rb = r0 + tt*16 + quad*4;
            const long long p  = rb >> 3;           // local parent index
            #pragma unroll
            for (int nt = 0; nt < 8; ++nt){
                int col = nt*16 + l15;
                float b = bxr[nt];
                float h0 = relu(acc[tt][nt][0]+b), h1 = relu(acc[tt][nt][1]+b);
                float h2 = relu(acc[tt][nt][2]+b), h3 = relu(acc[tt][nt][3]+b);
                float s = h0 + h1 + h2 + h3;
                float ch = (float)ctxh[p*DIM + col];
                ctx[(child_base + rb  )*DIM + col] = tobf((ch + s - h0)*0.25f);
                ctx[(child_base + rb+1)*DIM + col] = tobf((ch + s - h1)*0.25f);
                ctx[(child_base + rb+2)*DIM + col] = tobf((ch + s - h2)*0.25f);
                ctx[(child_base + rb+3)*DIM + col] = tobf((ch + s - h3)*0.25f);
            }
        }
    }
}

// final: out = relu([ctx,agg] @ Wf^T + bf) @ Wh^T + bh — both Wf halves resident
__global__ __launch_bounds__(512, 4) void final2_kernel(
    const __bf16* __restrict__ wfm,     // Wf frag-major, 2 halves x 16384
    const __bf16* __restrict__ ctx, const __bf16* __restrict__ agg,
    const float* __restrict__ bf_,
    const float* __restrict__ Wh, const float* __restrict__ bh,
    float* __restrict__ out)
{
    __shared__ __attribute__((aligned(16))) __bf16 lds_w[32768];
    {
        const int t = threadIdx.x;
        #pragma unroll
        for (int i = 0; i < 8; ++i){
            int c = i*512 + t;
            *((uint4*)lds_w + c) = *((const uint4*)wfm + c);
        }
    }
    __syncthreads();
    const int t = threadIdx.x, w = t>>6, lane = t&63, quad = lane>>4, l15 = lane&15;
    float bfr[8], whr[8];
    #pragma unroll
    for (int nt = 0; nt < 8; ++nt){
        bfr[nt] = bf_[nt*16 + l15];
        whr[nt] = Wh[nt*16 + l15];
    }
    const float bb = bh[0];
    const int gw = blockIdx.x*8 + w;        // 4688 waves, 9376 tiles
    #pragma unroll 1
    for (int k = 0; k < 2; ++k){
        const long long tile = gw + (long long)k*4688;
        const long long r0 = tile*32;
        if (r0 >= NTOT) break;
        f32x4 acc[2][8];
        #pragma unroll
        for (int tt = 0; tt < 2; ++tt)
            #pragma unroll
            for (int i = 0; i < 8; ++i) acc[tt][i] = f32x4{0.f,0.f,0.f,0.f};
        #pragma unroll
        for (int half = 0; half < 2; ++half){
            const __bf16* src = half ? agg : ctx;
            bf16x8 a[2][4];
            #pragma unroll
            for (int tt = 0; tt < 2; ++tt){
                long long r = r0 + tt*16 + l15;
                if (r >= NTOT) r = NTOT - 1;
                #pragma unroll
                for (int ks = 0; ks < 4; ++ks)
                    a[tt][ks] = *(const bf16x8*)(src + r*DIM + ks*32 + quad*8);
            }
            #pragma unroll
            for (int ks = 0; ks < 4; ++ks){
                #pragma unroll
                for (int nt = 0; nt < 8; ++nt){
                    bf16x8 b = *(const bf16x8*)&lds_w[half*16384 + ((nt*4+ks)<<9) + lane*8];
                    mfma_acc(acc[0][nt], a[0][ks], b);
                    mfma_acc(acc[1][nt], a[1][ks], b);
                }
            }
        }
        #pragma unroll
        for (int tt = 0; tt < 2; ++tt){
            float p0 = 0.f, p1 = 0.f, p2 = 0.f, p3 = 0.f;
            #pragma unroll
            for (int nt = 0; nt < 8; ++nt){
                float b = bfr[nt], wh = whr[nt];
                p0 += relu(acc[tt][nt][0]+b)*wh;
                p1 += relu(acc[tt][nt][1]+b)*wh;
                p2 += relu(acc[tt][nt][2]+b)*wh;
                p3 += relu(acc[tt][nt][3]+b)*wh;
            }
            #pragma unroll
            for (int m = 1; m < 16; m <<= 1){
                p0 += __shfl_xor(p0, m);
                p1 += __shfl_xor(p1, m);
                p2 += __shfl_xor(p2, m);
                p3 += __shfl_xor(p3, m);
            }
            if (l15 == 0){
                long long r = r0 + tt*16 + quad*4;
                if (r   < NTOT) out[r  ] = p0 + bb;
                if (r+1 < NTOT) out[r+1] = p1 + bb;
                if (r+2 < NTOT) out[r+2] = p2 + bb;
                if (r+3 < NTOT) out[r+3] = p3 + bb;
            }
        }
    }
}

// ================== fused small-level kernels (round-0 proven) ==================

__global__ __launch_bounds__(256, 3) void up_f(
    const __bf16* __restrict__ wts,     // Ws @0, Wc @16384 (row-major)
    const float* __restrict__ init,
    const float* __restrict__ bs, const float* __restrict__ bc,
    __bf16* __restrict__ agg,
    long long child_base, long long parent_base, long long n_par)
{
    __shared__ __bf16 lds_w[128*LPAD];
    __shared__ __bf16 lds_sib[32*LPAD];

    const int t = threadIdx.x;
    const int w = t >> 6, lane = t & 63, quad = lane >> 4, l15 = lane & 15;

    load_w_lds(wts, lds_w, 128);                // Ws
    __syncthreads();

    const long long n_child = n_par * 8;
    const long long rowbase = (long long)blockIdx.x*128 + w*32;

    f32x4 acc[2][8];
    #pragma unroll
    for (int tt = 0; tt < 2; ++tt)
        #pragma unroll
        for (int i = 0; i < 8; ++i) acc[tt][i] = f32x4{0.f,0.f,0.f,0.f};

    bf16x8 af[2][4];
    #pragma unroll
    for (int tt = 0; tt < 2; ++tt){
        long long r = rowbase + tt*16 + l15;
        if (r >= n_child) r = n_child - 1;
        const long long base = (child_base + r)*DIM;
        #pragma unroll
        for (int ks = 0; ks < 4; ++ks)
            af[tt][ks] = *(const bf16x8*)(agg + base + ks*32 + quad*8);
    }
    #pragma unroll
    for (int ks = 0; ks < 4; ++ks){
        #pragma unroll
        for (int nt = 0; nt < 8; ++nt){
            bf16x8 bfrag = *(const bf16x8*)&lds_w[(nt*16 + l15)*LPAD + ks*32 + quad*8];
            mfma_acc(acc[0][nt], af[0][ks], bfrag);
            mfma_acc(acc[1][nt], af[1][ks], bfrag);
        }
    }
    #pragma unroll
    for (int tt = 0; tt < 2; ++tt){
        const int g = w*8 + tt*4 + quad;
        #pragma unroll
        for (int nt = 0; nt < 8; ++nt){
            int col = nt*16 + l15;
            float b = bs[col];
            float s = relu(acc[tt][nt][0]+b) + relu(acc[tt][nt][1]+b)
                    + relu(acc[tt][nt][2]+b) + relu(acc[tt][nt][3]+b);
            lds_sib[g*LPAD + col] = tobf(s * 0.25f);
        }
    }
    __syncthreads();
    load_w_lds(wts + 16384, lds_w, 128);        // Wc (reuse LDS)
    __syncthreads();

    if (w < 2){
        f32x4 a2c[8];
        #pragma unroll
        for (int i = 0; i < 8; ++i) a2c[i] = f32x4{0.f,0.f,0.f,0.f};
        bf16x8 a2[4];
        #pragma unroll
        for (int ks = 0; ks < 4; ++ks)
            a2[ks] = *(const bf16x8*)&lds_sib[(w*16 + l15)*LPAD + ks*32 + quad*8];
        #pragma unroll
        for (int ks = 0; ks < 4; ++ks){
            #pragma unroll
            for (int nt = 0; nt < 8; ++nt){
                bf16x8 bfrag = *(const bf16x8*)&lds_w[(nt*16 + l15)*LPAD + ks*32 + quad*8];
                mfma_acc(a2c[nt], a2[ks], bfrag);
            }
        }
        const long long p0 = (long long)blockIdx.x*16 + w*8 + quad*2;
        const long long p1 = p0 + 1;
        #pragma unroll
        for (int nt = 0; nt < 8; ++nt){
            int col = nt*16 + l15;
            float b = bc[col];
            float r0 = relu(a2c[nt][0]+b), r1 = relu(a2c[nt][1]+b);
            float r2 = relu(a2c[nt][2]+b), r3 = relu(a2c[nt][3]+b);
            if (p0 < n_par){
                long long gr = parent_base + p0;
                agg[gr*DIM + col] = tobf(init[gr*DIM + col] + 0.5f*(r0+r1));
            }
            if (p1 < n_par){
                long long gr = parent_base + p1;
                agg[gr*DIM + col] = tobf(init[gr*DIM + col] + 0.5f*(r2+r3));
            }
        }
    }
}

__global__ __launch_bounds__(256, 3) void down_f(
    const __bf16* __restrict__ wts,     // Wx @32768 (row-major)
    const float* __restrict__ bx,
    const __bf16* __restrict__ agg,
    __bf16* __restrict__ ctx,
    long long parent_base, long long child_base, long long n_par)
{
    __shared__ __bf16 lds_w[128*LPAD];
    __shared__ float lds_ctxh[16*132];

    const int t = threadIdx.x;
    const int w = t >> 6, lane = t & 63, quad = lane >> 4, l15 = lane & 15;

    load_w_lds(wts + 32768, lds_w, 128);        // Wx
    __syncthreads();

    const long long n_child = n_par*8;

    if (w == 0){
        f32x4 acc[8];
        #pragma unroll
        for (int i = 0; i < 8; ++i) acc[i] = f32x4{0.f,0.f,0.f,0.f};
        bf16x8 a[4];
        long long p = (long long)blockIdx.x*16 + l15;
        if (p >= n_par) p = n_par - 1;
        #pragma unroll
        for (int ks = 0; ks < 4; ++ks)
            a[ks] = *(const bf16x8*)(ctx + (parent_base + p)*DIM + ks*32 + quad*8);
        #pragma unroll
        for (int ks = 0; ks < 4; ++ks){
            #pragma unroll
            for (int nt = 0; nt < 8; ++nt){
                bf16x8 bfrag = *(const bf16x8*)&lds_w[(nt*16 + l15)*LPAD + ks*32 + quad*8];
                mfma_acc(acc[nt], a[ks], bfrag);
            }
        }
        #pragma unroll
        for (int nt = 0; nt < 8; ++nt){
            int col = nt*16 + l15;
            float b = bx[col];
            #pragma unroll
            for (int rg = 0; rg < 4; ++rg)
                lds_ctxh[(quad*4 + rg)*132 + col] = relu(acc[nt][rg] + b);
        }
    }
    __syncthreads();

    f32x4 acc[2][8];
    #pragma unroll
    for (int tt = 0; tt < 2; ++tt)
        #pragma unroll
        for (int i = 0; i < 8; ++i) acc[tt][i] = f32x4{0.f,0.f,0.f,0.f};
    bf16x8 a[2][4];
    const long long rowbase = (long long)blockIdx.x*128 + w*32;
    #pragma unroll
    for (int tt = 0; tt < 2; ++tt){
        long long r = rowbase + tt*16 + l15;
        if (r >= n_child) r = n_child - 1;
        #pragma unroll
        for (int ks = 0; ks < 4; ++ks)
            a[tt][ks] = *(const bf16x8*)(agg + (child_base + r)*DIM + ks*32 + quad*8);
    }
    #pragma unroll
    for (int ks = 0; ks < 4; ++ks){
        #pragma unroll
        for (int nt = 0; nt < 8; ++nt){
            bf16x8 bfrag = *(const bf16x8*)&lds_w[(nt*16 + l15)*LPAD + ks*32 + quad*8];
            mfma_acc(acc[0][nt], a[0][ks], bfrag);
            mfma_acc(acc[1][nt], a[1][ks], bfrag);
        }
    }
    #pragma unroll
    for (int tt = 0; tt < 2; ++tt){
        const long long rb = rowbase + tt*16 + quad*4;
        const int p_loc = w*4 + tt*2 + (quad >> 1);
        #pragma unroll
        for (int nt = 0; nt < 8; ++nt){
            int col = nt*16 + l15;
            float b = bx[col];
            float h0 = relu(acc[tt][nt][0]+b), h1 = relu(acc[tt][nt][1]+b);
            float h2 = relu(acc[tt][nt][2]+b), h3 = relu(acc[tt][nt][3]+b);
            float s = h0 + h1 + h2 + h3;
            float ch = lds_ctxh[p_loc*132 + col];
            if (rb   < n_child) ctx[(child_base + rb  )*DIM + col] = tobf((ch + s - h0)*0.25f);
            if (rb+1 < n_child) ctx[(child_base + rb+1)*DIM + col] = tobf((ch + s - h1)*0.25f);
            if (rb+2 < n_child) ctx[(child_base + rb+2)*DIM + col] = tobf((ch + s - h2)*0.25f);
            if (rb+3 < n_child) ctx[(child_base + rb+3)*DIM + col] = tobf((ch + s - h3)*0.25f);
        }
    }
}

extern "C" void kernel_launch(void* const* d_in, const int* in_sizes, int n_in,
                              void* d_out, int out_size, void* d_ws, size_t ws_size,
                              hipStream_t stream)
{
    const float* init = (const float*)d_in[0];
    const float* Ws  = (const float*)d_in[1];
    const float* bs  = (const float*)d_in[2];
    const float* Wc  = (const float*)d_in[3];
    const float* bc  = (const float*)d_in[4];
    const float* Wx  = (const float*)d_in[5];
    const float* bx  = (const float*)d_in[6];
    const float* Wf  = (const float*)d_in[7];
    const float* bff = (const float*)d_in[8];
    const float* Wh  = (const float*)d_in[9];
    const float* bh  = (const float*)d_in[10];
    float* out = (float*)d_out;

    // ws layout: agg bf16 [N,128] | ctx bf16 [N,128] | wts row-major (81920)
    //            | wts frag-major (81920) | ctxh bf16 [32768,128]
    // sib tmp aliases the leaf-ctx region (up-phase only; leaf ctx written later).
    __bf16* agg  = (__bf16*)d_ws;
    __bf16* ctx  = agg + NTOT*DIM;
    __bf16* wts  = ctx + NTOT*DIM;
    __bf16* wfm  = wts + 81920;
    __bf16* ctxh = wfm + 81920;
    __bf16* sib  = ctx + 37449LL*DIM;

    static const long long SZ[7] = {1,8,64,512,4096,32768,262144};
    static const long long OF[8] = {0,1,9,73,585,4681,37449,299593};

    prep_kernel<<<dim3(641), dim3(256), 0, stream>>>(Ws, Wc, Wx, Wf, wts, ctx);

    // ---- up: leaf level split into two streaming kernels ----
    up1_kernel<<<dim3(1024), dim3(256), 0, stream>>>(wfm, init, bs, agg, sib, OF[6]);
    up2_kernel<<<dim3(512),  dim3(256), 0, stream>>>(wfm + 16384, init, bc, sib, agg, OF[5]);
    for (int l = 4; l >= 0; --l){
        int blocks = (int)((SZ[l]*8 + 127)/128);
        up_f<<<dim3(blocks), dim3(256), 0, stream>>>(
            wts, init, bs, bc, agg, OF[l+1], OF[l], SZ[l]);
    }
    // ---- down: small levels fused, leaf level split ----
    for (int l = 0; l < 5; ++l){
        int blocks = (int)((SZ[l]*8 + 127)/128);
        down_f<<<dim3(blocks), dim3(256), 0, stream>>>(
            wts, bx, agg, ctx, OF[l], OF[l+1], SZ[l]);
    }
    downh_kernel<<<dim3(256),  dim3(256), 0, stream>>>(wfm + 32768, bx, ctx, ctxh, OF[5]);
    downc_kernel<<<dim3(1024), dim3(256), 0, stream>>>(wfm + 32768, bx, agg, ctxh, ctx, OF[6]);

    final2_kernel<<<dim3(586), dim3(512), 0, stream>>>(
        wfm + 49152, ctx, agg, bff, Wh, bh, out);
}

// Round 3
// 480.193 us; speedup vs baseline: 1.2384x; 1.2384x over previous
//
#include <hip/hip_runtime.h>
#include <stdint.h>

#define DIM 128
#define LPAD 136   // padded LDS row stride for the fused small-level kernels (round-0 proven)

static constexpr long long NTOT = 299593LL;

using bf16x8 = __attribute__((ext_vector_type(8))) __bf16;
using f32x4  = __attribute__((ext_vector_type(4))) float;

__device__ __forceinline__ float relu(float x){ return x > 0.f ? x : 0.f; }
__device__ __forceinline__ __bf16 tobf(float x){ return (__bf16)x; }

__device__ __forceinline__ void mfma_acc(f32x4& acc, bf16x8 a, bf16x8 b){
    acc = __builtin_amdgcn_mfma_f32_16x16x32_bf16(a, b, acc, 0, 0, 0);
}

// XOR swizzle for a private 16x128 bf16 LDS slice: spreads rows across banks.
// Bijective within the row; identical function applied on write and read.
__device__ __forceinline__ int swz(int row, int col){
    return row*128 + (col ^ ((row & 7) << 3));
}

// copy 128x128 bf16 weight (row stride src_stride) into padded LDS (stride LPAD)
// -- used only by the fused small-level kernels (round-0 layout)
__device__ __forceinline__ void load_w_lds(const __bf16* __restrict__ wsrc,
                                           __bf16* lds, int src_stride){
    int t = threadIdx.x;
    #pragma unroll
    for (int i = 0; i < 8; ++i){
        int idx = t + i*256;                 // 2048 chunks of 8 bf16
        int row = idx >> 4, col8 = (idx & 15) << 3;
        *(uint4*)(&lds[row*LPAD + col8]) = *(const uint4*)(wsrc + row*src_stride + col8);
    }
}

// stage a 32KB frag-major weight into LDS: straight contiguous copy, conflict-free
template<int NTHR>
__device__ __forceinline__ void stage_fm(const __bf16* __restrict__ src, __bf16* lds){
    const int t = threadIdx.x;
    #pragma unroll
    for (int i = 0; i < 2048/NTHR; ++i){
        int c = i*NTHR + t;
        *((uint4*)lds + c) = *((const uint4*)src + c);
    }
}

// ---- prep: weights fp32->bf16 in BOTH row-major (fused small kernels) and
// frag-major (leaf/final kernels) layouts; root ctx = ones.
// Frag-major: element (r,c) -> ((nt*4+ks)*512 + lane*8 + j), nt=r>>4, l15=r&15,
// ks=c>>5, quad=(c>>3)&3, j=c&7, lane=quad*16+l15.  (verified round 2)
__global__ __launch_bounds__(256) void prep_kernel(
    const float* __restrict__ Ws, const float* __restrict__ Wc,
    const float* __restrict__ Wx, const float* __restrict__ Wf,
    __bf16* __restrict__ wts, __bf16* __restrict__ ctx)
{
    int idx = blockIdx.x*256 + threadIdx.x;
    if (idx < 81920){
        float v;
        if      (idx < 16384) v = Ws[idx];
        else if (idx < 32768) v = Wc[idx - 16384];
        else if (idx < 49152) v = Wx[idx - 32768];
        else                  v = Wf[idx - 49152];
        wts[idx] = tobf(v);
    } else if (idx < 163840){
        int d2 = idx - 81920;
        int sel = d2 >> 14;                 // 0:Ws 1:Wc 2:Wx 3:Wf-h0 4:Wf-h1
        int d   = d2 & 16383;
        int j = d & 7, ln = (d >> 3) & 63, f = d >> 9;
        int r = (f >> 2)*16 + (ln & 15);
        int c = (f & 3)*32 + (ln >> 4)*8 + j;
        float v;
        if      (sel == 0) v = Ws[r*128 + c];
        else if (sel == 1) v = Wc[r*128 + c];
        else if (sel == 2) v = Wx[r*128 + c];
        else if (sel == 3) v = Wf[r*256 + c];
        else               v = Wf[r*256 + 128 + c];
        wts[idx] = tobf(v);
    } else if (idx < 163968){
        ctx[idx - 163840] = tobf(1.0f);     // root context row
    }
}

// ================== leaf kernels: barrier-free wave-fused streaming ==================

// upleaf: per wave, 64 child rows -> GEMM1(Ws) -> 16 sib rows in PRIVATE LDS slice
// (same-wave ds ordering, no barrier) -> GEMM2(Wc) -> 8 parent rows.
// Both weights resident (64KB frag-major). One barrier total (post-stage).
__global__ __launch_bounds__(256, 2) void upleaf_kernel(
    const __bf16* __restrict__ wfm,     // Ws @0, Wc @16384 (frag-major)
    const float* __restrict__ init,
    const float* __restrict__ bs, const float* __restrict__ bc,
    __bf16* __restrict__ agg)
{
    __shared__ __attribute__((aligned(16))) __bf16 lds_w[32768];    // Ws | Wc
    __shared__ __attribute__((aligned(16))) __bf16 lds_sib[4*2048]; // per-wave 16x128
    {
        const int t = threadIdx.x;
        #pragma unroll
        for (int i = 0; i < 16; ++i){       // 64KB = 4096 uint4
            int c = i*256 + t;
            *((uint4*)lds_w + c) = *((const uint4*)wfm + c);
        }
    }
    __syncthreads();                        // the ONLY barrier

    const int t = threadIdx.x, w = t>>6, lane = t&63, quad = lane>>4, l15 = lane&15;
    const int sboff = w*2048;

    float bsr[8], bcr[8];
    #pragma unroll
    for (int nt = 0; nt < 8; ++nt){ bsr[nt] = bs[nt*16 + l15]; bcr[nt] = bc[nt*16 + l15]; }

    const long long gw = blockIdx.x*4 + w;  // 4096 waves, 64 rows each (exact)
    const long long r0 = gw*64;
    const long long cb = 37449LL;           // leaf base
    const long long pb = 4681LL + gw*8;     // this wave's 8 parents (global rows)

    // hoist parent init reads (used only in the GEMM2 epilogue)
    const long long pr0 = pb + quad*2, pr1 = pr0 + 1;
    float pinit0[8], pinit1[8];
    #pragma unroll
    for (int nt = 0; nt < 8; ++nt){
        pinit0[nt] = init[pr0*DIM + nt*16 + l15];
        pinit1[nt] = init[pr1*DIM + nt*16 + l15];
    }

    // batch-load & convert all 64 rows' A-frags; write leaf agg = bf16(init)
    bf16x8 af[4][4];
    #pragma unroll
    for (int tt = 0; tt < 4; ++tt){
        const long long base = (cb + r0 + tt*16 + l15)*DIM + quad*8;
        const float* p = init + base;
        #pragma unroll
        for (int ks = 0; ks < 4; ++ks){
            float4 v0 = *(const float4*)(p + ks*32);
            float4 v1 = *(const float4*)(p + ks*32 + 4);
            bf16x8 a;
            a[0]=tobf(v0.x); a[1]=tobf(v0.y); a[2]=tobf(v0.z); a[3]=tobf(v0.w);
            a[4]=tobf(v1.x); a[5]=tobf(v1.y); a[6]=tobf(v1.z); a[7]=tobf(v1.w);
            af[tt][ks] = a;
            *(uint4*)(agg + base + ks*32) = *(uint4*)&a;
        }
    }

    // GEMM1 in two halves (acc regs reused); sib rows -> private LDS slice
    #pragma unroll
    for (int h = 0; h < 2; ++h){
        f32x4 acc[2][8];
        #pragma unroll
        for (int u = 0; u < 2; ++u)
            #pragma unroll
            for (int i = 0; i < 8; ++i) acc[u][i] = f32x4{0.f,0.f,0.f,0.f};
        #pragma unroll
        for (int ks = 0; ks < 4; ++ks){
            #pragma unroll
            for (int nt = 0; nt < 8; ++nt){
                bf16x8 b = *(const bf16x8*)&lds_w[((nt*4+ks)<<9) + lane*8];
                mfma_acc(acc[0][nt], af[2*h+0][ks], b);
                mfma_acc(acc[1][nt], af[2*h+1][ks], b);
            }
        }
        #pragma unroll
        for (int u = 0; u < 2; ++u){
            const int row = (2*h+u)*4 + quad;   // local sib row 0..15
            #pragma unroll
            for (int nt = 0; nt < 8; ++nt){
                float b = bsr[nt];
                float s = relu(acc[u][nt][0]+b) + relu(acc[u][nt][1]+b)
                        + relu(acc[u][nt][2]+b) + relu(acc[u][nt][3]+b);
                lds_sib[sboff + swz(row, nt*16 + l15)] = tobf(s*0.25f);
            }
        }
    }

    // GEMM2: 16 sib rows -> 16 tactic outputs -> 8 parents (intra-wave, lgkmcnt-ordered)
    bf16x8 a2[4];
    #pragma unroll
    for (int ks = 0; ks < 4; ++ks)
        a2[ks] = *(const bf16x8*)&lds_sib[sboff + swz(l15, ks*32 + quad*8)];
    f32x4 ac2[8];
    #pragma unroll
    for (int i = 0; i < 8; ++i) ac2[i] = f32x4{0.f,0.f,0.f,0.f};
    #pragma unroll
    for (int ks = 0; ks < 4; ++ks){
        #pragma unroll
        for (int nt = 0; nt < 8; ++nt){
            bf16x8 b = *(const bf16x8*)&lds_w[16384 + ((nt*4+ks)<<9) + lane*8];
            mfma_acc(ac2[nt], a2[ks], b);
        }
    }
    #pragma unroll
    for (int nt = 0; nt < 8; ++nt){
        int col = nt*16 + l15;
        float b = bcr[nt];
        float r0_ = relu(ac2[nt][0]+b), r1_ = relu(ac2[nt][1]+b);
        float r2_ = relu(ac2[nt][2]+b), r3_ = relu(ac2[nt][3]+b);
        agg[pr0*DIM + col] = tobf(pinit0[nt] + 0.5f*(r0_+r1_));
        agg[pr1*DIM + col] = tobf(pinit1[nt] + 0.5f*(r2_+r3_));
    }
}

// downleaf: per wave, 16 parents -> ctxh in PRIVATE LDS slice (no barrier),
// then 8 child tiles: h = relu(Wx.agg+bx); ctx = (ctxh + sum_sibs - h)/4.
__global__ __launch_bounds__(256, 3) void downleaf_kernel(
    const __bf16* __restrict__ wfm,     // Wx frag-major
    const float* __restrict__ bx,
    const __bf16* __restrict__ agg,
    __bf16* __restrict__ ctx)
{
    __shared__ __attribute__((aligned(16))) __bf16 lds_w[16384];
    __shared__ __attribute__((aligned(16))) __bf16 lds_ch[4*2048];  // per-wave 16x128
    stage_fm<256>(wfm, lds_w);
    __syncthreads();                        // the ONLY barrier

    const int t = threadIdx.x, w = t>>6, lane = t&63, quad = lane>>4, l15 = lane&15;
    const int choff = w*2048;

    float bxr[8];
    #pragma unroll
    for (int nt = 0; nt < 8; ++nt) bxr[nt] = bx[nt*16 + l15];

    const long long gw = blockIdx.x*4 + w;  // 2048 waves, 128 child rows each (exact)
    const long long c0 = gw*128;
    const long long cb = 37449LL;
    const long long pg = 4681LL + gw*16;    // this wave's 16 parents (global rows)

    // ctxh tile: 16 parents
    {
        bf16x8 ap[4];
        #pragma unroll
        for (int ks = 0; ks < 4; ++ks)
            ap[ks] = *(const bf16x8*)(ctx + (pg + l15)*DIM + ks*32 + quad*8);
        f32x4 acp[8];
        #pragma unroll
        for (int i = 0; i < 8; ++i) acp[i] = f32x4{0.f,0.f,0.f,0.f};
        #pragma unroll
        for (int ks = 0; ks < 4; ++ks){
            #pragma unroll
            for (int nt = 0; nt < 8; ++nt){
                bf16x8 b = *(const bf16x8*)&lds_w[((nt*4+ks)<<9) + lane*8];
                mfma_acc(acp[nt], ap[ks], b);
            }
        }
        #pragma unroll
        for (int nt = 0; nt < 8; ++nt){
            float b = bxr[nt];
            #pragma unroll
            for (int rg = 0; rg < 4; ++rg){
                int row = quad*4 + rg;          // local parent 0..15
                lds_ch[choff + swz(row, nt*16 + l15)] = tobf(relu(acp[nt][rg] + b));
            }
        }
    }

    // 8 child tiles (intra-wave ctxh read, lgkmcnt-ordered; no barrier)
    #pragma unroll 2
    for (int ct = 0; ct < 8; ++ct){
        bf16x8 a[4];
        #pragma unroll
        for (int ks = 0; ks < 4; ++ks)
            a[ks] = *(const bf16x8*)(agg + (cb + c0 + ct*16 + l15)*DIM + ks*32 + quad*8);
        f32x4 acc[8];
        #pragma unroll
        for (int i = 0; i < 8; ++i) acc[i] = f32x4{0.f,0.f,0.f,0.f};
        #pragma unroll
        for (int ks = 0; ks < 4; ++ks){
            #pragma unroll
            for (int nt = 0; nt < 8; ++nt){
                bf16x8 b = *(const bf16x8*)&lds_w[((nt*4+ks)<<9) + lane*8];
                mfma_acc(acc[nt], a[ks], b);
            }
        }
        const long long rb = c0 + ct*16 + quad*4;       // one tactic's 4 siblings
        const int p_loc = ct*2 + (quad >> 1);           // local parent of these rows
        #pragma unroll
        for (int nt = 0; nt < 8; ++nt){
            int col = nt*16 + l15;
            float b = bxr[nt];
            float h0 = relu(acc[nt][0]+b), h1 = relu(acc[nt][1]+b);
            float h2 = relu(acc[nt][2]+b), h3 = relu(acc[nt][3]+b);
            float s = h0 + h1 + h2 + h3;
            float ch = (float)lds_ch[choff + swz(p_loc, col)];
            ctx[(cb + rb  )*DIM + col] = tobf((ch + s - h0)*0.25f);
            ctx[(cb + rb+1)*DIM + col] = tobf((ch + s - h1)*0.25f);
            ctx[(cb + rb+2)*DIM + col] = tobf((ch + s - h2)*0.25f);
            ctx[(cb + rb+3)*DIM + col] = tobf((ch + s - h3)*0.25f);
        }
    }
}

// final: out = relu([ctx,agg] @ Wf^T + bf) @ Wh^T + bh — both Wf halves resident,
// single stage + barrier, then pure streaming (round-2 structure).
__global__ __launch_bounds__(512, 4) void final2_kernel(
    const __bf16* __restrict__ wfm,     // Wf frag-major, 2 halves x 16384
    const __bf16* __restrict__ ctx, const __bf16* __restrict__ agg,
    const float* __restrict__ bf_,
    const float* __restrict__ Wh, const float* __restrict__ bh,
    float* __restrict__ out)
{
    __shared__ __attribute__((aligned(16))) __bf16 lds_w[32768];
    {
        const int t = threadIdx.x;
        #pragma unroll
        for (int i = 0; i < 8; ++i){
            int c = i*512 + t;
            *((uint4*)lds_w + c) = *((const uint4*)wfm + c);
        }
    }
    __syncthreads();
    const int t = threadIdx.x, w = t>>6, lane = t&63, quad = lane>>4, l15 = lane&15;
    float bfr[8], whr[8];
    #pragma unroll
    for (int nt = 0; nt < 8; ++nt){
        bfr[nt] = bf_[nt*16 + l15];
        whr[nt] = Wh[nt*16 + l15];
    }
    const float bb = bh[0];
    const int gw = blockIdx.x*8 + w;        // 4688 waves, 9376 tiles
    #pragma unroll 1
    for (int k = 0; k < 2; ++k){
        const long long tile = gw + (long long)k*4688;
        const long long r0 = tile*32;
        if (r0 >= NTOT) break;
        f32x4 acc[2][8];
        #pragma unroll
        for (int tt = 0; tt < 2; ++tt)
            #pragma unroll
            for (int i = 0; i < 8; ++i) acc[tt][i] = f32x4{0.f,0.f,0.f,0.f};
        #pragma unroll
        for (int half = 0; half < 2; ++half){
            const __bf16* src = half ? agg : ctx;
            bf16x8 a[2][4];
            #pragma unroll
            for (int tt = 0; tt < 2; ++tt){
                long long r = r0 + tt*16 + l15;
                if (r >= NTOT) r = NTOT - 1;
                #pragma unroll
                for (int ks = 0; ks < 4; ++ks)
                    a[tt][ks] = *(const bf16x8*)(src + r*DIM + ks*32 + quad*8);
            }
            #pragma unroll
            for (int ks = 0; ks < 4; ++ks){
                #pragma unroll
                for (int nt = 0; nt < 8; ++nt){
                    bf16x8 b = *(const bf16x8*)&lds_w[half*16384 + ((nt*4+ks)<<9) + lane*8];
                    mfma_acc(acc[0][nt], a[0][ks], b);
                    mfma_acc(acc[1][nt], a[1][ks], b);
                }
            }
        }
        #pragma unroll
        for (int tt = 0; tt < 2; ++tt){
            float p0 = 0.f, p1 = 0.f, p2 = 0.f, p3 = 0.f;
            #pragma unroll
            for (int nt = 0; nt < 8; ++nt){
                float b = bfr[nt], wh = whr[nt];
                p0 += relu(acc[tt][nt][0]+b)*wh;
                p1 += relu(acc[tt][nt][1]+b)*wh;
                p2 += relu(acc[tt][nt][2]+b)*wh;
                p3 += relu(acc[tt][nt][3]+b)*wh;
            }
            #pragma unroll
            for (int m = 1; m < 16; m <<= 1){
                p0 += __shfl_xor(p0, m);
                p1 += __shfl_xor(p1, m);
                p2 += __shfl_xor(p2, m);
                p3 += __shfl_xor(p3, m);
            }
            if (l15 == 0){
                long long r = r0 + tt*16 + quad*4;
                if (r   < NTOT) out[r  ] = p0 + bb;
                if (r+1 < NTOT) out[r+1] = p1 + bb;
                if (r+2 < NTOT) out[r+2] = p2 + bb;
                if (r+3 < NTOT) out[r+3] = p3 + bb;
            }
        }
    }
}

// ================== fused small-level kernels (round-0 proven) ==================

__global__ __launch_bounds__(256, 3) void up_f(
    const __bf16* __restrict__ wts,     // Ws @0, Wc @16384 (row-major)
    const float* __restrict__ init,
    const float* __restrict__ bs, const float* __restrict__ bc,
    __bf16* __restrict__ agg,
    long long child_base, long long parent_base, long long n_par)
{
    __shared__ __bf16 lds_w[128*LPAD];
    __shared__ __bf16 lds_sib[32*LPAD];

    const int t = threadIdx.x;
    const int w = t >> 6, lane = t & 63, quad = lane >> 4, l15 = lane & 15;

    load_w_lds(wts, lds_w, 128);                // Ws
    __syncthreads();

    const long long n_child = n_par * 8;
    const long long rowbase = (long long)blockIdx.x*128 + w*32;

    f32x4 acc[2][8];
    #pragma unroll
    for (int tt = 0; tt < 2; ++tt)
        #pragma unroll
        for (int i = 0; i < 8; ++i) acc[tt][i] = f32x4{0.f,0.f,0.f,0.f};

    bf16x8 af[2][4];
    #pragma unroll
    for (int tt = 0; tt < 2; ++tt){
        long long r = rowbase + tt*16 + l15;
        if (r >= n_child) r = n_child - 1;
        const long long base = (child_base + r)*DIM;
        #pragma unroll
        for (int ks = 0; ks < 4; ++ks)
            af[tt][ks] = *(const bf16x8*)(agg + base + ks*32 + quad*8);
    }
    #pragma unroll
    for (int ks = 0; ks < 4; ++ks){
        #pragma unroll
        for (int nt = 0; nt < 8; ++nt){
            bf16x8 bfrag = *(const bf16x8*)&lds_w[(nt*16 + l15)*LPAD + ks*32 + quad*8];
            mfma_acc(acc[0][nt], af[0][ks], bfrag);
            mfma_acc(acc[1][nt], af[1][ks], bfrag);
        }
    }
    #pragma unroll
    for (int tt = 0; tt < 2; ++tt){
        const int g = w*8 + tt*4 + quad;
        #pragma unroll
        for (int nt = 0; nt < 8; ++nt){
            int col = nt*16 + l15;
            float b = bs[col];
            float s = relu(acc[tt][nt][0]+b) + relu(acc[tt][nt][1]+b)
                    + relu(acc[tt][nt][2]+b) + relu(acc[tt][nt][3]+b);
            lds_sib[g*LPAD + col] = tobf(s * 0.25f);
        }
    }
    __syncthreads();
    load_w_lds(wts + 16384, lds_w, 128);        // Wc (reuse LDS)
    __syncthreads();

    if (w < 2){
        f32x4 a2c[8];
        #pragma unroll
        for (int i = 0; i < 8; ++i) a2c[i] = f32x4{0.f,0.f,0.f,0.f};
        bf16x8 a2[4];
        #pragma unroll
        for (int ks = 0; ks < 4; ++ks)
            a2[ks] = *(const bf16x8*)&lds_sib[(w*16 + l15)*LPAD + ks*32 + quad*8];
        #pragma unroll
        for (int ks = 0; ks < 4; ++ks){
            #pragma unroll
            for (int nt = 0; nt < 8; ++nt){
                bf16x8 bfrag = *(const bf16x8*)&lds_w[(nt*16 + l15)*LPAD + ks*32 + quad*8];
                mfma_acc(a2c[nt], a2[ks], bfrag);
            }
        }
        const long long p0 = (long long)blockIdx.x*16 + w*8 + quad*2;
        const long long p1 = p0 + 1;
        #pragma unroll
        for (int nt = 0; nt < 8; ++nt){
            int col = nt*16 + l15;
            float b = bc[col];
            float r0 = relu(a2c[nt][0]+b), r1 = relu(a2c[nt][1]+b);
            float r2 = relu(a2c[nt][2]+b), r3 = relu(a2c[nt][3]+b);
            if (p0 < n_par){
                long long gr = parent_base + p0;
                agg[gr*DIM + col] = tobf(init[gr*DIM + col] + 0.5f*(r0+r1));
            }
            if (p1 < n_par){
                long long gr = parent_base + p1;
                agg[gr*DIM + col] = tobf(init[gr*DIM + col] + 0.5f*(r2+r3));
            }
        }
    }
}

__global__ __launch_bounds__(256, 3) void down_f(
    const __bf16* __restrict__ wts,     // Wx @32768 (row-major)
    const float* __restrict__ bx,
    const __bf16* __restrict__ agg,
    __bf16* __restrict__ ctx,
    long long parent_base, long long child_base, long long n_par)
{
    __shared__ __bf16 lds_w[128*LPAD];
    __shared__ float lds_ctxh[16*132];

    const int t = threadIdx.x;
    const int w = t >> 6, lane = t & 63, quad = lane >> 4, l15 = lane & 15;

    load_w_lds(wts + 32768, lds_w, 128);        // Wx
    __syncthreads();

    const long long n_child = n_par*8;

    if (w == 0){
        f32x4 acc[8];
        #pragma unroll
        for (int i = 0; i < 8; ++i) acc[i] = f32x4{0.f,0.f,0.f,0.f};
        bf16x8 a[4];
        long long p = (long long)blockIdx.x*16 + l15;
        if (p >= n_par) p = n_par - 1;
        #pragma unroll
        for (int ks = 0; ks < 4; ++ks)
            a[ks] = *(const bf16x8*)(ctx + (parent_base + p)*DIM + ks*32 + quad*8);
        #pragma unroll
        for (int ks = 0; ks < 4; ++ks){
            #pragma unroll
            for (int nt = 0; nt < 8; ++nt){
                bf16x8 bfrag = *(const bf16x8*)&lds_w[(nt*16 + l15)*LPAD + ks*32 + quad*8];
                mfma_acc(acc[nt], a[ks], bfrag);
            }
        }
        #pragma unroll
        for (int nt = 0; nt < 8; ++nt){
            int col = nt*16 + l15;
            float b = bx[col];
            #pragma unroll
            for (int rg = 0; rg < 4; ++rg)
                lds_ctxh[(quad*4 + rg)*132 + col] = relu(acc[nt][rg] + b);
        }
    }
    __syncthreads();

    f32x4 acc[2][8];
    #pragma unroll
    for (int tt = 0; tt < 2; ++tt)
        #pragma unroll
        for (int i = 0; i < 8; ++i) acc[tt][i] = f32x4{0.f,0.f,0.f,0.f};
    bf16x8 a[2][4];
    const long long rowbase = (long long)blockIdx.x*128 + w*32;
    #pragma unroll
    for (int tt = 0; tt < 2; ++tt){
        long long r = rowbase + tt*16 + l15;
        if (r >= n_child) r = n_child - 1;
        #pragma unroll
        for (int ks = 0; ks < 4; ++ks)
            a[tt][ks] = *(const bf16x8*)(agg + (child_base + r)*DIM + ks*32 + quad*8);
    }
    #pragma unroll
    for (int ks = 0; ks < 4; ++ks){
        #pragma unroll
        for (int nt = 0; nt < 8; ++nt){
            bf16x8 bfrag = *(const bf16x8*)&lds_w[(nt*16 + l15)*LPAD + ks*32 + quad*8];
            mfma_acc(acc[0][nt], a[0][ks], bfrag);
            mfma_acc(acc[1][nt], a[1][ks], bfrag);
        }
    }
    #pragma unroll
    for (int tt = 0; tt < 2; ++tt){
        const long long rb = rowbase + tt*16 + quad*4;
        const int p_loc = w*4 + tt*2 + (quad >> 1);
        #pragma unroll
        for (int nt = 0; nt < 8; ++nt){
            int col = nt*16 + l15;
            float b = bx[col];
            float h0 = relu(acc[tt][nt][0]+b), h1 = relu(acc[tt][nt][1]+b);
            float h2 = relu(acc[tt][nt][2]+b), h3 = relu(acc[tt][nt][3]+b);
            float s = h0 + h1 + h2 + h3;
            float ch = lds_ctxh[p_loc*132 + col];
            if (rb   < n_child) ctx[(child_base + rb  )*DIM + col] = tobf((ch + s - h0)*0.25f);
            if (rb+1 < n_child) ctx[(child_base + rb+1)*DIM + col] = tobf((ch + s - h1)*0.25f);
            if (rb+2 < n_child) ctx[(child_base + rb+2)*DIM + col] = tobf((ch + s - h2)*0.25f);
            if (rb+3 < n_child) ctx[(child_base + rb+3)*DIM + col] = tobf((ch + s - h3)*0.25f);
        }
    }
}

extern "C" void kernel_launch(void* const* d_in, const int* in_sizes, int n_in,
                              void* d_out, int out_size, void* d_ws, size_t ws_size,
                              hipStream_t stream)
{
    const float* init = (const float*)d_in[0];
    const float* Ws  = (const float*)d_in[1];
    const float* bs  = (const float*)d_in[2];
    const float* Wc  = (const float*)d_in[3];
    const float* bc  = (const float*)d_in[4];
    const float* Wx  = (const float*)d_in[5];
    const float* bx  = (const float*)d_in[6];
    const float* Wf  = (const float*)d_in[7];
    const float* bff = (const float*)d_in[8];
    const float* Wh  = (const float*)d_in[9];
    const float* bh  = (const float*)d_in[10];
    float* out = (float*)d_out;

    // ws layout: agg bf16 [N,128] | ctx bf16 [N,128] | wts row-major (81920)
    //            | wts frag-major (81920)
    __bf16* agg  = (__bf16*)d_ws;
    __bf16* ctx  = agg + NTOT*DIM;
    __bf16* wts  = ctx + NTOT*DIM;
    __bf16* wfm  = wts + 81920;

    static const long long SZ[7] = {1,8,64,512,4096,32768,262144};
    static const long long OF[8] = {0,1,9,73,585,4681,37449,299593};

    prep_kernel<<<dim3(641), dim3(256), 0, stream>>>(Ws, Wc, Wx, Wf, wts, ctx);

    // ---- up: leaf level barrier-free wave-fused; smaller levels round-0 fused ----
    upleaf_kernel<<<dim3(1024), dim3(256), 0, stream>>>(wfm, init, bs, bc, agg);
    for (int l = 4; l >= 0; --l){
        int blocks = (int)((SZ[l]*8 + 127)/128);
        up_f<<<dim3(blocks), dim3(256), 0, stream>>>(
            wts, init, bs, bc, agg, OF[l+1], OF[l], SZ[l]);
    }
    // ---- down: smaller levels round-0 fused; leaf level barrier-free ----
    for (int l = 0; l < 5; ++l){
        int blocks = (int)((SZ[l]*8 + 127)/128);
        down_f<<<dim3(blocks), dim3(256), 0, stream>>>(
            wts, bx, agg, ctx, OF[l], OF[l+1], SZ[l]);
    }
    downleaf_kernel<<<dim3(512), dim3(256), 0, stream>>>(wfm + 32768, bx, agg, ctx);

    final2_kernel<<<dim3(586), dim3(512), 0, stream>>>(
        wfm + 49152, ctx, agg, bff, Wh, bh, out);
}